// Round 17
// baseline (250.353 us; speedup 1.0000x reference)
//
#include <hip/hip_runtime.h>
#include <cstdint>

#define V_TH 1.0f
#define RHO 0.9f
#define ADAPT 0.1f

static constexpr int B = 64, T = 8, C = 2, H = 128, W = 128;
static constexpr int H1 = 64, W1 = 64;
static constexpr int H2 = 32, W2 = 32;
static constexpr int FLAT = 32 * H2 * W2;   // 32768
static constexpr int R = B * T;             // 512

// workspace layout (bytes)
static constexpr size_t OFF_TRIP  = 0;                          // u64 [512*64*32] = 8 MB
static constexpr size_t OFF_BITS  = OFF_TRIP + 8388608;         // u32 [512*1024]  = 2 MB
static constexpr size_t OFF_PWT   = OFF_BITS + 2097152;         // f32 [32768*64]  = 8 MB
static constexpr size_t OFF_CNT   = OFF_PWT + 8388608;
static constexpr size_t OFF_TBL   = OFF_CNT + 256;              // f32 [12*4096*32] = 6 MB
static constexpr size_t OFF_PART  = OFF_TBL + 6291456;          // f32 [64*64*8*64] = 8 MB

// ---------------- mega1: conv1+LIF1 (2 lanes/px) | transpose | cnt | table --
// blocks: [0,2048) conv1, [2048,2560) transpose, 2560 cnt, [2561,2753) table
__global__ __launch_bounds__(256) void k_mega1(
    const float* __restrict__ x, const float* __restrict__ w,
    const float* __restrict__ bias, const float* __restrict__ beta,
    uint64_t* __restrict__ trip,
    const float* __restrict__ pw, float* __restrict__ pwt,
    const float* __restrict__ c2w, float* __restrict__ tbl,
    unsigned int* __restrict__ cnt) {
  __shared__ float shmem[64 * 65];          // conv1: sw1 + s1m; transpose: tile
  int bid = blockIdx.x;
  int tid = threadIdx.x;
  if (bid < 2048) {
    float* sw1 = shmem;                     // [j][c], row stride 68 (1224 fl)
    uint16_t* s1m = (uint16_t*)(shmem + 1280);   // [2][64] u16 = 256 B
    for (int i = tid; i < 288; i += 256) {
      int c = i / 18, j = i % 18;           // source linear i = c*18 + j
      sw1[j * 68 + c] = w[i];
    }
    __syncthreads();
    int b = bid >> 5;
    int rp = bid & 31;                      // rows 2rp, 2rp+1
    int lane = tid & 63;
    int lrow = tid >> 7;                    // 0/1: row within pair
    int half = (tid >> 6) & 1;              // w1 half
    int p = lane >> 1;                      // px within half-row, 0..31
    int ch = lane & 1;                      // channel half: ch*8 .. ch*8+7
    int h1 = rp * 2 + lrow;
    int w1 = half * 32 + p;
    float bias_r[8], beta_r[8];
#pragma unroll
    for (int c = 0; c < 8; ++c) { bias_r[c] = bias[ch * 8 + c];
                                  beta_r[c] = beta[ch * 8 + c]; }
    float mem[8], bth[8];
#pragma unroll
    for (int c = 0; c < 8; ++c) { mem[c] = 0.f; bth[c] = 0.f; }
    for (int t = 0; t < T; ++t) {
      int r = b * T + t;
      const float* xb = x + (size_t)(r * 2) * 16384;   // + ci*16384 + y*128
      uint32_t M = 0;
#pragma unroll
      for (int ci = 0; ci < 2; ++ci) {
#pragma unroll
        for (int kh = 0; kh < 3; ++kh) {
          int y = 2 * h1 - 1 + kh;
          uint32_t w3 = 0;
          if (y >= 0 && y < H) {
            const float* rowp = xb + ci * 16384 + y * 128;
            float2 v = *(const float2*)(rowp + 2 * w1);
            float nl = __shfl(v.y, lane - 2, 64);      // left px, same ch half
            if (p == 0) nl = (w1 > 0) ? rowp[2 * w1 - 1] : 0.f;
            uint32_t bl = (w1 > 0 && nl != 0.f) ? 1u : 0u;
            uint32_t bm = (v.x != 0.f) ? 2u : 0u;
            uint32_t br = (v.y != 0.f) ? 4u : 0u;
            w3 = bl | bm | br;
          }
          M |= w3 << ((ci * 3 + kh) * 3);
        }
      }
      float acc[8];
#pragma unroll
      for (int c = 0; c < 8; ++c) acc[c] = bias_r[c];
      while (M) {                           // ascending j == (ci,kh,kw) order
        int j = __ffs(M) - 1; M &= M - 1;
        const float4* wr = (const float4*)&sw1[j * 68 + ch * 8];
        float4 a0 = wr[0], a1 = wr[1];
        acc[0] += a0.x; acc[1] += a0.y; acc[2] += a0.z; acc[3] += a0.w;
        acc[4] += a1.x; acc[5] += a1.y; acc[6] += a1.z; acc[7] += a1.w;
      }
      uint32_t mask8 = 0;
#pragma unroll
      for (int c = 0; c < 8; ++c) {
        mem[c] = beta_r[c] * mem[c] + acc[c];
        float th = V_TH + bth[c];
        bool s = (mem[c] >= th);
        if (s) { mem[c] -= th; mask8 |= (1u << c); }
        bth[c] = RHO * bth[c] + (s ? ADAPT : 0.f);
      }
      uint32_t other = (uint32_t)__shfl((int)mask8, lane ^ 1, 64);
      if (ch == 0)
        s1m[lrow * 64 + w1] = (uint16_t)(mask8 | (other << 8));
      __syncthreads();
      if (tid < 64) {
        int row = tid >> 5, w2 = tid & 31;
        const uint16_t* sr = &s1m[row * 64];
        uint64_t m0 = (w2 > 0) ? sr[2 * w2 - 1] : 0u;
        uint64_t m1 = sr[2 * w2];
        uint64_t m2 = sr[2 * w2 + 1];
        trip[(size_t)(r * 64 + rp * 2 + row) * 32 + w2] =
            m0 | (m1 << 16) | (m2 << 32);
      }
      __syncthreads();
    }
  } else if (bid < 2560) {
    // transpose with channel permutation pos(c)=(c&3)*8+(c>>2):
    // pwt[(p*32+pos(c))*64+d] = pw[d*32768 + c*1024 + p]
    float* tile = shmem;
    int tb = bid - 2048;
    int c = tb >> 4, pt = tb & 15;
    int posc = ((c & 3) << 3) + (c >> 2);
    int p0 = pt * 64;
    int lane = tid & 63, quad = tid >> 6;
#pragma unroll
    for (int it = 0; it < 16; ++it) {
      int d = it * 4 + quad;
      tile[d * 65 + lane] = pw[(size_t)d * FLAT + c * 1024 + p0 + lane];
    }
    __syncthreads();
#pragma unroll
    for (int it = 0; it < 16; ++it) {
      int pp = it * 4 + quad;
      pwt[((size_t)((p0 + pp) * 32 + posc)) * 64 + lane] = tile[lane * 65 + pp];
    }
  } else if (bid == 2560) {
    if (tid == 0) *cnt = 0u;
  } else {
    // conv2 12-bit table: tbl[((kh*4+gp)*4096+v)*32+co] = sum of group's cols
    int idx = bid - 2561;               // 0..191
    int g = idx >> 4;                   // 0..11 = kh*4+gp
    int kh = g >> 2, gp = g & 3;
    int v = ((idx & 15) << 8) + tid;    // 0..4095
    float e[32];
#pragma unroll
    for (int co = 0; co < 32; ++co) e[co] = 0.f;
    for (int i = 0; i < 12; ++i) {
      if ((v >> i) & 1) {
        int j = gp * 12 + i;            // trip bit = kw*16 + ci
        int kw = j >> 4, ci = j & 15;
#pragma unroll
        for (int co = 0; co < 32; ++co)
          e[co] += c2w[((co * 16 + ci) * 3 + kh) * 3 + kw];
      }
    }
#pragma unroll
    for (int co = 0; co < 32; ++co)
      tbl[((size_t)(g * 4096 + v)) * 32 + co] = e[co];
  }
}

// ---------------- stage 2: conv(16->32,s2,p1) via 12-bit tables, 8 px/wave --
// 3 independent accumulator quads (one per kh) -> 12 loads in flight.
__global__ __launch_bounds__(256) void k_conv2_lif2(
    const uint64_t* __restrict__ trip, const float* __restrict__ tbl,
    const float* __restrict__ bias, const float* __restrict__ beta,
    uint32_t* __restrict__ bits, unsigned int* __restrict__ cnt) {
  __shared__ unsigned int sc;
  int tid = threadIdx.x;
  if (tid == 0) sc = 0u;
  __syncthreads();
  int lane = tid & 63;
  int li = lane & 7;
  int p8 = lane >> 3;
  int wvi = (blockIdx.x * 256 + tid) >> 6;
  int px = wvi * 8 + p8;
  int w2 = px & 31, h2 = (px >> 5) & 31, b = px >> 10;
  float4 b4 = *(const float4*)&bias[4 * li];
  float4 bt4 = *(const float4*)&beta[4 * li];
  float m0v = 0.f, m1v = 0.f, m2v = 0.f, m3v = 0.f;
  float t0 = 0.f, t1 = 0.f, t2 = 0.f, t3 = 0.f;
  unsigned int lc = 0;
  const float4* tb4 = (const float4*)tbl;   // [g][v][li] float4
  for (int t = 0; t < T; ++t) {
    int r = b * T + t;
    const uint64_t* tr = trip + (size_t)(r * 64 + 2 * h2) * 32 + w2;
    uint64_t q0 = (h2 > 0) ? tr[-32] : 0ull;
    uint64_t q1 = tr[0];
    uint64_t q2 = tr[32];
    uint32_t r0l = (uint32_t)q0, r0h = (uint32_t)(q0 >> 32);
    uint32_t r1l = (uint32_t)q1, r1h = (uint32_t)(q1 >> 32);
    uint32_t r2l = (uint32_t)q2, r2h = (uint32_t)(q2 >> 32);
    float4 v0 = tb4[(0 << 15) + ((r0l & 4095u) << 3) + li];
    float4 v1 = tb4[(1 << 15) + (((r0l >> 12) & 4095u) << 3) + li];
    float4 v2 = tb4[(2 << 15) + ((((r0l >> 24) | (r0h << 8)) & 4095u) << 3) + li];
    float4 v3 = tb4[(3 << 15) + (((r0h >> 4) & 4095u) << 3) + li];
    float4 v4 = tb4[(4 << 15) + ((r1l & 4095u) << 3) + li];
    float4 v5 = tb4[(5 << 15) + (((r1l >> 12) & 4095u) << 3) + li];
    float4 v6 = tb4[(6 << 15) + ((((r1l >> 24) | (r1h << 8)) & 4095u) << 3) + li];
    float4 v7 = tb4[(7 << 15) + (((r1h >> 4) & 4095u) << 3) + li];
    float4 v8 = tb4[(8 << 15) + ((r2l & 4095u) << 3) + li];
    float4 v9 = tb4[(9 << 15) + (((r2l >> 12) & 4095u) << 3) + li];
    float4 va = tb4[(10 << 15) + ((((r2l >> 24) | (r2h << 8)) & 4095u) << 3) + li];
    float4 vb = tb4[(11 << 15) + (((r2h >> 4) & 4095u) << 3) + li];
    float A0 = b4.x + v0.x + v1.x + v2.x + v3.x;
    float A1 = b4.y + v0.y + v1.y + v2.y + v3.y;
    float A2 = b4.z + v0.z + v1.z + v2.z + v3.z;
    float A3 = b4.w + v0.w + v1.w + v2.w + v3.w;
    float B0 = v4.x + v5.x + v6.x + v7.x;
    float B1 = v4.y + v5.y + v6.y + v7.y;
    float B2 = v4.z + v5.z + v6.z + v7.z;
    float B3 = v4.w + v5.w + v6.w + v7.w;
    float C0 = v8.x + v9.x + va.x + vb.x;
    float C1 = v8.y + v9.y + va.y + vb.y;
    float C2 = v8.z + v9.z + va.z + vb.z;
    float C3 = v8.w + v9.w + va.w + vb.w;
    float a0 = (A0 + B0) + C0, a1 = (A1 + B1) + C1;
    float a2 = (A2 + B2) + C2, a3 = (A3 + B3) + C3;
    m0v = bt4.x * m0v + a0;
    m1v = bt4.y * m1v + a1;
    m2v = bt4.z * m2v + a2;
    m3v = bt4.w * m3v + a3;
    float th0 = V_TH + t0, th1 = V_TH + t1, th2 = V_TH + t2, th3 = V_TH + t3;
    bool s0 = (m0v >= th0), s1 = (m1v >= th1), s2 = (m2v >= th2), s3 = (m3v >= th3);
    if (s0) m0v -= th0;
    if (s1) m1v -= th1;
    if (s2) m2v -= th2;
    if (s3) m3v -= th3;
    t0 = RHO * t0 + (s0 ? ADAPT : 0.f);
    t1 = RHO * t1 + (s1 ? ADAPT : 0.f);
    t2 = RHO * t2 + (s2 ? ADAPT : 0.f);
    t3 = RHO * t3 + (s3 ? ADAPT : 0.f);
    unsigned long long bl0 = __ballot(s0);
    unsigned long long bl1 = __ballot(s1);
    unsigned long long bl2 = __ballot(s2);
    unsigned long long bl3 = __ballot(s3);
    if (li == 0) {
      int sh = p8 * 8;
      uint32_t m32 = ((uint32_t)(bl0 >> sh) & 0xFFu)
                   | (((uint32_t)(bl1 >> sh) & 0xFFu) << 8)
                   | (((uint32_t)(bl2 >> sh) & 0xFFu) << 16)
                   | (((uint32_t)(bl3 >> sh) & 0xFFu) << 24);
      bits[(size_t)r * 1024 + (px & 1023)] = m32;
      lc += __popc(m32);
    }
  }
  if (li == 0) atomicAdd(&sc, lc);
  __syncthreads();
  if (tid == 0) atomicAdd(cnt, sc);
}

// ---------------- sparse proj GEMM: per-row scan, partials to ws ------------
__global__ __launch_bounds__(256) void k_proj_gemm(
    const uint32_t* __restrict__ bits, const float* __restrict__ pwt,
    float* __restrict__ partial) {
  int rt = blockIdx.x >> 4;
  int ks = (blockIdx.x & 15) * 4 + (threadIdx.x >> 6);
  int d = threadIdx.x & 63;
  float acc[8] = {0, 0, 0, 0, 0, 0, 0, 0};
  const uint32_t* bb = bits + (size_t)rt * 8 * 1024;
  for (int wi = 0; wi < 16; ++wi) {
    int word = ks * 16 + wi;
    const float* rowbase = pwt + ((size_t)word * 32) * 64 + d;
#pragma unroll
    for (int ri = 0; ri < 8; ++ri) {
      uint32_t m = bb[ri * 1024 + word];
      while (m) {
        int c = __ffs(m) - 1; m &= m - 1;
        acc[ri] += rowbase[c << 6];
      }
    }
  }
#pragma unroll
  for (int ri = 0; ri < 8; ++ri)
    partial[((size_t)(rt * 64 + ks) * 8 + ri) * 64 + d] = acc[ri];
}

// ------- reduce + MHA + mean + output LIF + classifier + sparsity ----------
__global__ __launch_bounds__(256) void k_attn_final(
    const float* __restrict__ partial, const float* __restrict__ pb,
    const float* __restrict__ wq, const float* __restrict__ wk,
    const float* __restrict__ wv, const float* __restrict__ wo,
    const float* __restrict__ clsw, const float* __restrict__ clsb,
    const unsigned int* __restrict__ cnt, float* __restrict__ out) {
  __shared__ float swq[64 * 65], swk[64 * 65], swv[64 * 65], swo[64 * 65];
  __shared__ float sp[8 * 65], sq[8 * 65], sk[8 * 65], sv[8 * 65], so2[8 * 65];
  __shared__ float satt[4][8][8];
  __shared__ float sob[64];
  int b = blockIdx.x, tid = threadIdx.x;
  for (int i = tid; i < 4096; i += 256) {
    int dd = i >> 6, e = i & 63;
    swq[dd * 65 + e] = wq[i]; swk[dd * 65 + e] = wk[i];
    swv[dd * 65 + e] = wv[i]; swo[dd * 65 + e] = wo[i];
  }
  for (int i = tid; i < 512; i += 256) {
    int ri = i >> 6, d = i & 63;
    float s = pb[d];
    const float* p = partial + ((size_t)(b * 64) * 8 + ri) * 64 + d;
#pragma unroll
    for (int ks = 0; ks < 64; ++ks) s += p[(size_t)ks * 512];
    sp[ri * 65 + d] = s;
  }
  __syncthreads();
#pragma unroll
  for (int p = 0; p < 2; ++p) {
    int idx = p * 256 + tid, t = idx >> 6, d = idx & 63;
    float qa = 0.f, ka = 0.f, va = 0.f;
    for (int e = 0; e < 64; ++e) {
      float pe = sp[t * 65 + e];
      qa += pe * swq[d * 65 + e];
      ka += pe * swk[d * 65 + e];
      va += pe * swv[d * 65 + e];
    }
    sq[t * 65 + d] = qa; sk[t * 65 + d] = ka; sv[t * 65 + d] = va;
  }
  __syncthreads();
  {
    int h = tid >> 6, q = (tid >> 3) & 7, k = tid & 7;
    float s = 0.f;
    for (int j = 0; j < 16; ++j)
      s += sq[q * 65 + h * 16 + j] * sk[k * 65 + h * 16 + j];
    satt[h][q][k] = s * 0.25f;
  }
  __syncthreads();
  if (tid < 32) {
    int h = tid >> 3, q2 = tid & 7;
    float m = -1e30f;
    for (int k2 = 0; k2 < 8; ++k2) m = fmaxf(m, satt[h][q2][k2]);
    float sum = 0.f;
    for (int k2 = 0; k2 < 8; ++k2) {
      float e = expf(satt[h][q2][k2] - m);
      satt[h][q2][k2] = e; sum += e;
    }
    float inv = 1.f / sum;
    for (int k2 = 0; k2 < 8; ++k2) satt[h][q2][k2] *= inv;
  }
  __syncthreads();
#pragma unroll
  for (int p = 0; p < 2; ++p) {
    int idx = p * 256 + tid, t = idx >> 6, d = idx & 63;
    int h = d >> 4;
    float o = 0.f;
    for (int k = 0; k < 8; ++k) o += satt[h][t][k] * sv[k * 65 + d];
    so2[t * 65 + d] = o;
  }
  __syncthreads();
  if (tid < 64) {
    float ob = 0.f;
    for (int t = 0; t < 8; ++t) ob += so2[t * 65 + tid];
    sob[tid] = ob * 0.125f;
  }
  __syncthreads();
  if (tid < 64) {
    float ctx = 0.f;
    for (int e = 0; e < 64; ++e) ctx += sob[e] * swo[tid * 65 + e];
    int spk = (ctx >= V_TH) ? 1 : 0;
    unsigned long long ball = __ballot(spk);
    if (tid < 2) {
      float lg = clsb[tid];
      for (int dd = 0; dd < 64; ++dd)
        if ((ball >> dd) & 1ull) lg += clsw[tid * 64 + dd];
      out[b * 2 + tid] = lg;
    }
    if (b == 0 && tid == 2)
      out[128] = 1.f - (float)(*cnt) / 16777216.f;
  }
}

extern "C" void kernel_launch(void* const* d_in, const int* in_sizes, int n_in,
                              void* d_out, int out_size, void* d_ws, size_t ws_size,
                              hipStream_t stream) {
  const float* x    = (const float*)d_in[0];
  const float* c1w  = (const float*)d_in[1];
  const float* c1b  = (const float*)d_in[2];
  const float* c2w  = (const float*)d_in[3];
  const float* c2b  = (const float*)d_in[4];
  const float* bt1  = (const float*)d_in[5];
  const float* bt2  = (const float*)d_in[6];
  const float* pw   = (const float*)d_in[7];
  const float* pb   = (const float*)d_in[8];
  const float* wq   = (const float*)d_in[9];
  const float* wk   = (const float*)d_in[10];
  const float* wv   = (const float*)d_in[11];
  const float* wo   = (const float*)d_in[12];
  const float* clsw = (const float*)d_in[13];
  const float* clsb = (const float*)d_in[14];
  float* out = (float*)d_out;

  uint8_t* ws = (uint8_t*)d_ws;
  uint64_t* trip  = (uint64_t*)(ws + OFF_TRIP);
  uint32_t* bits  = (uint32_t*)(ws + OFF_BITS);
  float*    pwt   = (float*)(ws + OFF_PWT);
  unsigned int* cnt = (unsigned int*)(ws + OFF_CNT);
  float*    tbl   = (float*)(ws + OFF_TBL);
  float*    part  = (float*)(ws + OFF_PART);

  k_mega1<<<2753, 256, 0, stream>>>(x, c1w, c1b, bt1, trip, pw, pwt, c2w, tbl, cnt);
  k_conv2_lif2<<<2048, 256, 0, stream>>>(trip, tbl, c2b, bt2, bits, cnt);
  k_proj_gemm<<<1024, 256, 0, stream>>>(bits, pwt, part);
  k_attn_final<<<64, 256, 0, stream>>>(part, pb, wq, wk, wv, wo, clsw, clsb, cnt, out);
}

// Round 18
// 214.685 us; speedup vs baseline: 1.1661x; 1.1661x over previous
//
#include <hip/hip_runtime.h>
#include <cstdint>

#define V_TH 1.0f
#define RHO 0.9f
#define ADAPT 0.1f

static constexpr int B = 64, T = 8, C = 2, H = 128, W = 128;
static constexpr int H1 = 64, W1 = 64;
static constexpr int H2 = 32, W2 = 32;
static constexpr int FLAT = 32 * H2 * W2;   // 32768
static constexpr int R = B * T;             // 512

// workspace layout (bytes)
static constexpr size_t OFF_TRIP  = 0;                          // u64 [512*64*32] = 8 MB
static constexpr size_t OFF_BITS  = OFF_TRIP + 8388608;         // u32 [512*1024]  = 2 MB
static constexpr size_t OFF_PWT   = OFF_BITS + 2097152;         // f32 [32768*64]  = 8 MB
static constexpr size_t OFF_CNT   = OFF_PWT + 8388608;
static constexpr size_t OFF_TBL   = OFF_CNT + 256;              // f32 [12*4096*32] = 6 MB
static constexpr size_t OFF_PART  = OFF_TBL + 6291456;          // f32 [64*64*8*64] = 8 MB

// ---------------- mega1: conv1+LIF1 (direct x) | transpose | cnt | table12 --
// blocks: [0,1024) conv1, [1024,1536) transpose, 1536 cnt, [1537,1729) table
__global__ __launch_bounds__(256) void k_mega1(
    const float* __restrict__ x, const float* __restrict__ w,
    const float* __restrict__ bias, const float* __restrict__ beta,
    uint64_t* __restrict__ trip,
    const float* __restrict__ pw, float* __restrict__ pwt,
    const float* __restrict__ c2w, float* __restrict__ tbl,
    unsigned int* __restrict__ cnt) {
  __shared__ float shmem[64 * 65];          // conv1: sw1[18*68]; transpose: tile
  int bid = blockIdx.x;
  int tid = threadIdx.x;
  if (bid < 1024) {
    float* sw1 = shmem;                     // [j][c], row stride 68
    for (int i = tid; i < 288; i += 256) {
      int c = i / 18, j = i % 18;           // source linear i = c*18 + j
      sw1[j * 68 + c] = w[i];
    }
    __syncthreads();
    int gid = bid * 256 + tid;              // (b, h1, w1)
    int w1 = gid & 63, h1 = (gid >> 6) & 63, b = gid >> 12;
    int lane = tid & 63;
    float bias_r[16], beta_r[16];
#pragma unroll
    for (int c = 0; c < 16; ++c) { bias_r[c] = bias[c]; beta_r[c] = beta[c]; }
    float mem[16], bth[16];
#pragma unroll
    for (int c = 0; c < 16; ++c) { mem[c] = 0.f; bth[c] = 0.f; }
    for (int t = 0; t < T; ++t) {
      int r = b * T + t;
      const float* xb = x + (size_t)(r * 2) * 16384;   // + ci*16384 + y*128
      uint32_t M = 0;
#pragma unroll
      for (int ci = 0; ci < 2; ++ci) {
#pragma unroll
        for (int kh = 0; kh < 3; ++kh) {
          int y = 2 * h1 - 1 + kh;
          uint32_t w3 = 0;
          if (y >= 0 && y < H) {
            float2 v = *(const float2*)(xb + ci * 16384 + y * 128 + 2 * lane);
            float nl = __shfl(v.y, lane - 1, 64);      // left px from lane-1
            uint32_t bl = (lane > 0 && nl != 0.f) ? 1u : 0u;
            uint32_t bm = (v.x != 0.f) ? 2u : 0u;
            uint32_t br = (v.y != 0.f) ? 4u : 0u;
            w3 = bl | bm | br;
          }
          M |= w3 << ((ci * 3 + kh) * 3);
        }
      }
      float acc[16];
#pragma unroll
      for (int c = 0; c < 16; ++c) acc[c] = bias_r[c];
      while (M) {                           // ascending j == (ci,kh,kw) order
        int j = __ffs(M) - 1; M &= M - 1;
        const float4* wr = (const float4*)&sw1[j * 68];
        float4 a0 = wr[0], a1 = wr[1], a2 = wr[2], a3 = wr[3];
        acc[0] += a0.x; acc[1] += a0.y; acc[2] += a0.z; acc[3] += a0.w;
        acc[4] += a1.x; acc[5] += a1.y; acc[6] += a1.z; acc[7] += a1.w;
        acc[8] += a2.x; acc[9] += a2.y; acc[10] += a2.z; acc[11] += a2.w;
        acc[12] += a3.x; acc[13] += a3.y; acc[14] += a3.z; acc[15] += a3.w;
      }
      uint32_t mask = 0;
#pragma unroll
      for (int c = 0; c < 16; ++c) {
        mem[c] = beta_r[c] * mem[c] + acc[c];
        float th = V_TH + bth[c];
        bool s = (mem[c] >= th);
        if (s) { mem[c] -= th; mask |= (1u << c); }
        bth[c] = RHO * bth[c] + (s ? ADAPT : 0.f);
      }
      int iL = 2 * lane - 1; if (iL < 0) iL = 0;
      uint32_t mL = __shfl((int)mask, iL, 64);
      uint32_t mC = __shfl((int)mask, 2 * lane, 64);
      uint32_t mR = __shfl((int)mask, 2 * lane + 1, 64);
      if (lane < 32) {
        uint64_t tw = (uint64_t)(lane ? mL : 0u) | ((uint64_t)mC << 16) |
                      ((uint64_t)mR << 32);
        trip[(size_t)(r * H1 + h1) * 32 + lane] = tw;
      }
    }
  } else if (bid < 1536) {
    // transpose with channel permutation pos(c)=(c&3)*8+(c>>2):
    // pwt[(p*32+pos(c))*64+d] = pw[d*32768 + c*1024 + p]
    float* tile = shmem;
    int tb = bid - 1024;
    int c = tb >> 4, pt = tb & 15;
    int posc = ((c & 3) << 3) + (c >> 2);
    int p0 = pt * 64;
    int lane = tid & 63, quad = tid >> 6;
#pragma unroll
    for (int it = 0; it < 16; ++it) {
      int d = it * 4 + quad;
      tile[d * 65 + lane] = pw[(size_t)d * FLAT + c * 1024 + p0 + lane];
    }
    __syncthreads();
#pragma unroll
    for (int it = 0; it < 16; ++it) {
      int pp = it * 4 + quad;
      pwt[((size_t)((p0 + pp) * 32 + posc)) * 64 + lane] = tile[lane * 65 + pp];
    }
  } else if (bid == 1536) {
    if (tid == 0) *cnt = 0u;
  } else {
    // conv2 12-bit table: tbl[((kh*4+gp)*4096+v)*32+co] = sum of group's cols
    int idx = bid - 1537;               // 0..191
    int g = idx >> 4;                   // 0..11 = kh*4+gp
    int kh = g >> 2, gp = g & 3;
    int v = ((idx & 15) << 8) + tid;    // 0..4095
    float e[32];
#pragma unroll
    for (int co = 0; co < 32; ++co) e[co] = 0.f;
    for (int i = 0; i < 12; ++i) {
      if ((v >> i) & 1) {
        int j = gp * 12 + i;            // trip bit = kw*16 + ci
        int kw = j >> 4, ci = j & 15;
#pragma unroll
        for (int co = 0; co < 32; ++co)
          e[co] += c2w[((co * 16 + ci) * 3 + kh) * 3 + kw];
      }
    }
#pragma unroll
    for (int co = 0; co < 32; ++co)
      tbl[((size_t)(g * 4096 + v)) * 32 + co] = e[co];
  }
}

// ---------------- stage 2: conv(16->32,s2,p1) via 12-bit tables, 8 px/wave --
// 3 independent accumulator quads (one per kh) -> 12 loads in flight.
__global__ __launch_bounds__(256) void k_conv2_lif2(
    const uint64_t* __restrict__ trip, const float* __restrict__ tbl,
    const float* __restrict__ bias, const float* __restrict__ beta,
    uint32_t* __restrict__ bits, unsigned int* __restrict__ cnt) {
  __shared__ unsigned int sc;
  int tid = threadIdx.x;
  if (tid == 0) sc = 0u;
  __syncthreads();
  int lane = tid & 63;
  int li = lane & 7;
  int p8 = lane >> 3;
  int wvi = (blockIdx.x * 256 + tid) >> 6;
  int px = wvi * 8 + p8;
  int w2 = px & 31, h2 = (px >> 5) & 31, b = px >> 10;
  float4 b4 = *(const float4*)&bias[4 * li];
  float4 bt4 = *(const float4*)&beta[4 * li];
  float m0v = 0.f, m1v = 0.f, m2v = 0.f, m3v = 0.f;
  float t0 = 0.f, t1 = 0.f, t2 = 0.f, t3 = 0.f;
  unsigned int lc = 0;
  const float4* tb4 = (const float4*)tbl;   // [g][v][li] float4
  for (int t = 0; t < T; ++t) {
    int r = b * T + t;
    const uint64_t* tr = trip + (size_t)(r * 64 + 2 * h2) * 32 + w2;
    uint64_t q0 = (h2 > 0) ? tr[-32] : 0ull;
    uint64_t q1 = tr[0];
    uint64_t q2 = tr[32];
    uint32_t r0l = (uint32_t)q0, r0h = (uint32_t)(q0 >> 32);
    uint32_t r1l = (uint32_t)q1, r1h = (uint32_t)(q1 >> 32);
    uint32_t r2l = (uint32_t)q2, r2h = (uint32_t)(q2 >> 32);
    // issue all 12 independent loads, then fold per-kh chains
    float4 v0 = tb4[(0 << 15) + ((r0l & 4095u) << 3) + li];
    float4 v1 = tb4[(1 << 15) + (((r0l >> 12) & 4095u) << 3) + li];
    float4 v2 = tb4[(2 << 15) + ((((r0l >> 24) | (r0h << 8)) & 4095u) << 3) + li];
    float4 v3 = tb4[(3 << 15) + (((r0h >> 4) & 4095u) << 3) + li];
    float4 v4 = tb4[(4 << 15) + ((r1l & 4095u) << 3) + li];
    float4 v5 = tb4[(5 << 15) + (((r1l >> 12) & 4095u) << 3) + li];
    float4 v6 = tb4[(6 << 15) + ((((r1l >> 24) | (r1h << 8)) & 4095u) << 3) + li];
    float4 v7 = tb4[(7 << 15) + (((r1h >> 4) & 4095u) << 3) + li];
    float4 v8 = tb4[(8 << 15) + ((r2l & 4095u) << 3) + li];
    float4 v9 = tb4[(9 << 15) + (((r2l >> 12) & 4095u) << 3) + li];
    float4 va = tb4[(10 << 15) + ((((r2l >> 24) | (r2h << 8)) & 4095u) << 3) + li];
    float4 vb = tb4[(11 << 15) + (((r2h >> 4) & 4095u) << 3) + li];
    // kh0 chain (includes bias, preserving the old prefix order)
    float A0 = b4.x + v0.x + v1.x + v2.x + v3.x;
    float A1 = b4.y + v0.y + v1.y + v2.y + v3.y;
    float A2 = b4.z + v0.z + v1.z + v2.z + v3.z;
    float A3 = b4.w + v0.w + v1.w + v2.w + v3.w;
    // kh1 chain
    float B0 = v4.x + v5.x + v6.x + v7.x;
    float B1 = v4.y + v5.y + v6.y + v7.y;
    float B2 = v4.z + v5.z + v6.z + v7.z;
    float B3 = v4.w + v5.w + v6.w + v7.w;
    // kh2 chain
    float C0 = v8.x + v9.x + va.x + vb.x;
    float C1 = v8.y + v9.y + va.y + vb.y;
    float C2 = v8.z + v9.z + va.z + vb.z;
    float C3 = v8.w + v9.w + va.w + vb.w;
    float a0 = (A0 + B0) + C0, a1 = (A1 + B1) + C1;
    float a2 = (A2 + B2) + C2, a3 = (A3 + B3) + C3;
    m0v = bt4.x * m0v + a0;
    m1v = bt4.y * m1v + a1;
    m2v = bt4.z * m2v + a2;
    m3v = bt4.w * m3v + a3;
    float th0 = V_TH + t0, th1 = V_TH + t1, th2 = V_TH + t2, th3 = V_TH + t3;
    bool s0 = (m0v >= th0), s1 = (m1v >= th1), s2 = (m2v >= th2), s3 = (m3v >= th3);
    if (s0) m0v -= th0;
    if (s1) m1v -= th1;
    if (s2) m2v -= th2;
    if (s3) m3v -= th3;
    t0 = RHO * t0 + (s0 ? ADAPT : 0.f);
    t1 = RHO * t1 + (s1 ? ADAPT : 0.f);
    t2 = RHO * t2 + (s2 ? ADAPT : 0.f);
    t3 = RHO * t3 + (s3 ? ADAPT : 0.f);
    unsigned long long bl0 = __ballot(s0);
    unsigned long long bl1 = __ballot(s1);
    unsigned long long bl2 = __ballot(s2);
    unsigned long long bl3 = __ballot(s3);
    if (li == 0) {
      int sh = p8 * 8;
      uint32_t m32 = ((uint32_t)(bl0 >> sh) & 0xFFu)
                   | (((uint32_t)(bl1 >> sh) & 0xFFu) << 8)
                   | (((uint32_t)(bl2 >> sh) & 0xFFu) << 16)
                   | (((uint32_t)(bl3 >> sh) & 0xFFu) << 24);
      bits[(size_t)r * 1024 + (px & 1023)] = m32;
      lc += __popc(m32);
    }
  }
  if (li == 0) atomicAdd(&sc, lc);
  __syncthreads();
  if (tid == 0) atomicAdd(cnt, sc);
}

// ---------------- sparse proj GEMM: per-row scan, partials to ws ------------
// 1024 blocks x 256: block = (rt, 4 ks), wave = one ks split (16 words).
__global__ __launch_bounds__(256) void k_proj_gemm(
    const uint32_t* __restrict__ bits, const float* __restrict__ pwt,
    float* __restrict__ partial) {
  int rt = blockIdx.x >> 4;
  int ks = (blockIdx.x & 15) * 4 + (threadIdx.x >> 6);
  int d = threadIdx.x & 63;
  float acc[8] = {0, 0, 0, 0, 0, 0, 0, 0};
  const uint32_t* bb = bits + (size_t)rt * 8 * 1024;
  for (int wi = 0; wi < 16; ++wi) {
    int word = ks * 16 + wi;
    const float* rowbase = pwt + ((size_t)word * 32) * 64 + d;
#pragma unroll
    for (int ri = 0; ri < 8; ++ri) {
      uint32_t m = bb[ri * 1024 + word];
      while (m) {
        int c = __ffs(m) - 1; m &= m - 1;
        acc[ri] += rowbase[c << 6];
      }
    }
  }
#pragma unroll
  for (int ri = 0; ri < 8; ++ri)
    partial[((size_t)(rt * 64 + ks) * 8 + ri) * 64 + d] = acc[ri];
}

// ------- reduce + MHA + mean + output LIF + classifier + sparsity ----------
__global__ __launch_bounds__(256) void k_attn_final(
    const float* __restrict__ partial, const float* __restrict__ pb,
    const float* __restrict__ wq, const float* __restrict__ wk,
    const float* __restrict__ wv, const float* __restrict__ wo,
    const float* __restrict__ clsw, const float* __restrict__ clsb,
    const unsigned int* __restrict__ cnt, float* __restrict__ out) {
  __shared__ float swq[64 * 65], swk[64 * 65], swv[64 * 65], swo[64 * 65];
  __shared__ float sp[8 * 65], sq[8 * 65], sk[8 * 65], sv[8 * 65], so2[8 * 65];
  __shared__ float satt[4][8][8];
  __shared__ float sob[64];
  int b = blockIdx.x, tid = threadIdx.x;
  for (int i = tid; i < 4096; i += 256) {
    int dd = i >> 6, e = i & 63;
    swq[dd * 65 + e] = wq[i]; swk[dd * 65 + e] = wk[i];
    swv[dd * 65 + e] = wv[i]; swo[dd * 65 + e] = wo[i];
  }
  // fused proj reduction: sp[ri][d] = pb[d] + sum_ks partial[b][ks][ri][d]
  for (int i = tid; i < 512; i += 256) {
    int ri = i >> 6, d = i & 63;
    float s = pb[d];
    const float* p = partial + ((size_t)(b * 64) * 8 + ri) * 64 + d;
#pragma unroll
    for (int ks = 0; ks < 64; ++ks) s += p[(size_t)ks * 512];
    sp[ri * 65 + d] = s;
  }
  __syncthreads();
#pragma unroll
  for (int p = 0; p < 2; ++p) {
    int idx = p * 256 + tid, t = idx >> 6, d = idx & 63;
    float qa = 0.f, ka = 0.f, va = 0.f;
    for (int e = 0; e < 64; ++e) {
      float pe = sp[t * 65 + e];
      qa += pe * swq[d * 65 + e];
      ka += pe * swk[d * 65 + e];
      va += pe * swv[d * 65 + e];
    }
    sq[t * 65 + d] = qa; sk[t * 65 + d] = ka; sv[t * 65 + d] = va;
  }
  __syncthreads();
  {
    int h = tid >> 6, q = (tid >> 3) & 7, k = tid & 7;
    float s = 0.f;
    for (int j = 0; j < 16; ++j)
      s += sq[q * 65 + h * 16 + j] * sk[k * 65 + h * 16 + j];
    satt[h][q][k] = s * 0.25f;
  }
  __syncthreads();
  if (tid < 32) {
    int h = tid >> 3, q2 = tid & 7;
    float m = -1e30f;
    for (int k2 = 0; k2 < 8; ++k2) m = fmaxf(m, satt[h][q2][k2]);
    float sum = 0.f;
    for (int k2 = 0; k2 < 8; ++k2) {
      float e = expf(satt[h][q2][k2] - m);
      satt[h][q2][k2] = e; sum += e;
    }
    float inv = 1.f / sum;
    for (int k2 = 0; k2 < 8; ++k2) satt[h][q2][k2] *= inv;
  }
  __syncthreads();
#pragma unroll
  for (int p = 0; p < 2; ++p) {
    int idx = p * 256 + tid, t = idx >> 6, d = idx & 63;
    int h = d >> 4;
    float o = 0.f;
    for (int k = 0; k < 8; ++k) o += satt[h][t][k] * sv[k * 65 + d];
    so2[t * 65 + d] = o;
  }
  __syncthreads();
  if (tid < 64) {
    float ob = 0.f;
    for (int t = 0; t < 8; ++t) ob += so2[t * 65 + tid];
    sob[tid] = ob * 0.125f;
  }
  __syncthreads();
  if (tid < 64) {
    float ctx = 0.f;
    for (int e = 0; e < 64; ++e) ctx += sob[e] * swo[tid * 65 + e];
    int spk = (ctx >= V_TH) ? 1 : 0;
    unsigned long long ball = __ballot(spk);
    if (tid < 2) {
      float lg = clsb[tid];
      for (int dd = 0; dd < 64; ++dd)
        if ((ball >> dd) & 1ull) lg += clsw[tid * 64 + dd];
      out[b * 2 + tid] = lg;
    }
    if (b == 0 && tid == 2)
      out[128] = 1.f - (float)(*cnt) / 16777216.f;
  }
}

extern "C" void kernel_launch(void* const* d_in, const int* in_sizes, int n_in,
                              void* d_out, int out_size, void* d_ws, size_t ws_size,
                              hipStream_t stream) {
  const float* x    = (const float*)d_in[0];
  const float* c1w  = (const float*)d_in[1];
  const float* c1b  = (const float*)d_in[2];
  const float* c2w  = (const float*)d_in[3];
  const float* c2b  = (const float*)d_in[4];
  const float* bt1  = (const float*)d_in[5];
  const float* bt2  = (const float*)d_in[6];
  const float* pw   = (const float*)d_in[7];
  const float* pb   = (const float*)d_in[8];
  const float* wq   = (const float*)d_in[9];
  const float* wk   = (const float*)d_in[10];
  const float* wv   = (const float*)d_in[11];
  const float* wo   = (const float*)d_in[12];
  const float* clsw = (const float*)d_in[13];
  const float* clsb = (const float*)d_in[14];
  float* out = (float*)d_out;

  uint8_t* ws = (uint8_t*)d_ws;
  uint64_t* trip  = (uint64_t*)(ws + OFF_TRIP);
  uint32_t* bits  = (uint32_t*)(ws + OFF_BITS);
  float*    pwt   = (float*)(ws + OFF_PWT);
  unsigned int* cnt = (unsigned int*)(ws + OFF_CNT);
  float*    tbl   = (float*)(ws + OFF_TBL);
  float*    part  = (float*)(ws + OFF_PART);

  k_mega1<<<1729, 256, 0, stream>>>(x, c1w, c1b, bt1, trip, pw, pwt, c2w, tbl, cnt);
  k_conv2_lif2<<<2048, 256, 0, stream>>>(trip, tbl, c2b, bt2, bits, cnt);
  k_proj_gemm<<<1024, 256, 0, stream>>>(bits, pwt, part);
  k_attn_final<<<64, 256, 0, stream>>>(part, pb, wq, wk, wv, wo, clsw, clsb, cnt, out);
}